// Round 2
// baseline (4364.270 us; speedup 1.0000x reference)
//
#include <hip/hip_runtime.h>

#define N_NODES 100000
#define N_EDGES 3200000
#define IN_CH 128
#define HID_CH 64
#define OUT_CH 32

// ---------------- degree accumulation: deg[dst] += w ----------------
__global__ void deg_kernel(const int* __restrict__ dst, const float* __restrict__ w,
                           float* __restrict__ deg, int nE) {
    int i = blockIdx.x * blockDim.x + threadIdx.x;
    if (i < nE) atomicAdd(&deg[dst[i]], w[i]);
}

// ---------------- dinv[i] = rsqrt(deg[i] + 1)  (in place) ----------------
__global__ void dinv_kernel(float* __restrict__ deg, int n) {
    int i = blockIdx.x * blockDim.x + threadIdx.x;
    if (i < n) deg[i] = rsqrtf(deg[i] + 1.0f);
}

// ---------------- norm[e] = dinv[dst]*w*dinv[src] ----------------
__global__ void norm_kernel(const int* __restrict__ src, const int* __restrict__ dst,
                            const float* __restrict__ w, const float* __restrict__ dinv,
                            float* __restrict__ norm, int nE) {
    int i = blockIdx.x * blockDim.x + threadIdx.x;
    if (i < nE) norm[i] = dinv[dst[i]] * w[i] * dinv[src[i]];
}

// ---------------- skinny GEMM: H[n x OUTC] = X[n x INC] @ W[INC x OUTC] ----------------
// 64 rows per block, 256 threads. W and X tile staged in LDS.
// Thread tile: 4 rows x TN cols, TN = OUTC/16 (16 col-groups x 16 row-groups = 256).
template<int INC, int OUTC>
__global__ __launch_bounds__(256) void gemm_kernel(const float* __restrict__ X,
                                                   const float* __restrict__ Wm,
                                                   float* __restrict__ H, int n) {
    constexpr int TN = OUTC / 16;
    __shared__ float Ws[INC][OUTC];
    __shared__ float Xs[64][INC + 4];   // +4 pad: keeps 16B align, breaks bank aliasing

    const int tid = threadIdx.x;
    const int row0 = blockIdx.x * 64;

    // stage W (INC*OUTC floats, multiple of 4)
    for (int i = tid; i < INC * OUTC / 4; i += 256) {
        reinterpret_cast<float4*>(&Ws[0][0])[i] = reinterpret_cast<const float4*>(Wm)[i];
    }
    // stage X tile (64 x INC), float4, guard tail rows
    for (int i = tid; i < 64 * INC / 4; i += 256) {
        int r = i / (INC / 4);
        int c = (i % (INC / 4)) * 4;
        float4 v = make_float4(0.f, 0.f, 0.f, 0.f);
        if (row0 + r < n)
            v = *reinterpret_cast<const float4*>(X + (size_t)(row0 + r) * INC + c);
        *reinterpret_cast<float4*>(&Xs[r][c]) = v;
    }
    __syncthreads();

    const int cg = tid & 15;        // col group
    const int rg = tid >> 4;        // row group (4 rows each)

    float acc[4][TN];
#pragma unroll
    for (int i = 0; i < 4; ++i)
#pragma unroll
        for (int j = 0; j < TN; ++j) acc[i][j] = 0.f;

    for (int k = 0; k < INC; ++k) {
        float wv[TN];
#pragma unroll
        for (int j = 0; j < TN; ++j) wv[j] = Ws[k][cg * TN + j];
#pragma unroll
        for (int i = 0; i < 4; ++i) {
            float xv = Xs[rg * 4 + i][k];
#pragma unroll
            for (int j = 0; j < TN; ++j) acc[i][j] = fmaf(xv, wv[j], acc[i][j]);
        }
    }

#pragma unroll
    for (int i = 0; i < 4; ++i) {
        int row = row0 + rg * 4 + i;
        if (row < n) {
#pragma unroll
            for (int j = 0; j < TN; ++j)
                H[(size_t)row * OUTC + cg * TN + j] = acc[i][j];
        }
    }
}

// ---------------- edge scatter: agg[dst] += norm[e] * h[src], C channels ----------------
// C/4 threads per edge, each handles a float4 of channels.
template<int C>
__global__ void scatter_kernel(const int* __restrict__ src, const int* __restrict__ dst,
                               const float* __restrict__ norm, const float* __restrict__ H,
                               float* __restrict__ AGG, int nE) {
    constexpr int TPE = C / 4;
    long long t = (long long)blockIdx.x * blockDim.x + threadIdx.x;
    int e = (int)(t / TPE);
    int c4 = (int)(t % TPE) * 4;
    if (e >= nE) return;
    int s = src[e], d = dst[e];
    float nr = norm[e];
    float4 hv = *reinterpret_cast<const float4*>(H + (size_t)s * C + c4);
    float* out = AGG + (size_t)d * C + c4;
    atomicAdd(out + 0, nr * hv.x);
    atomicAdd(out + 1, nr * hv.y);
    atomicAdd(out + 2, nr * hv.z);
    atomicAdd(out + 3, nr * hv.w);
}

// ---------------- finalize: out = agg + dinv^2 * h + b  (+ optional relu) ----------------
template<int C, bool RELU>
__global__ void finalize_kernel(const float* __restrict__ agg, const float* __restrict__ h,
                                const float* __restrict__ dinv, const float* __restrict__ bias,
                                float* __restrict__ out, int n) {
    int t = blockIdx.x * blockDim.x + threadIdx.x;
    int total = n * (C / 4);
    if (t >= total) return;
    int row = t / (C / 4);
    int c4 = (t % (C / 4)) * 4;
    float di = dinv[row];
    float di2 = di * di;
    float4 a = *reinterpret_cast<const float4*>(agg + (size_t)row * C + c4);
    float4 hv = *reinterpret_cast<const float4*>(h + (size_t)row * C + c4);
    float4 b = *reinterpret_cast<const float4*>(bias + c4);
    float4 r;
    r.x = fmaf(di2, hv.x, a.x) + b.x;
    r.y = fmaf(di2, hv.y, a.y) + b.y;
    r.z = fmaf(di2, hv.z, a.z) + b.z;
    r.w = fmaf(di2, hv.w, a.w) + b.w;
    if (RELU) {
        r.x = fmaxf(r.x, 0.f); r.y = fmaxf(r.y, 0.f);
        r.z = fmaxf(r.z, 0.f); r.w = fmaxf(r.w, 0.f);
    }
    *reinterpret_cast<float4*>(out + (size_t)row * C + c4) = r;
}

extern "C" void kernel_launch(void* const* d_in, const int* in_sizes, int n_in,
                              void* d_out, int out_size, void* d_ws, size_t ws_size,
                              hipStream_t stream) {
    const float* x   = (const float*)d_in[0];
    const int*   ei  = (const int*)d_in[1];
    const float* w   = (const float*)d_in[2];
    const float* W1  = (const float*)d_in[3];
    const float* b1  = (const float*)d_in[4];
    const float* W2  = (const float*)d_in[5];
    const float* b2  = (const float*)d_in[6];
    float* out = (float*)d_out;

    const int* src = ei;            // edge_index[0]
    const int* dst = ei + N_EDGES;  // edge_index[1]

    // workspace layout (256B aligned chunks)
    char* ws = (char*)d_ws;
    size_t off = 0;
    auto alloc = [&](size_t bytes) { size_t p = off; off += (bytes + 255) & ~(size_t)255; return p; };
    float* deg   = (float*)(ws + alloc((size_t)N_NODES * 4));            // -> dinv in place
    float* norm  = (float*)(ws + alloc((size_t)N_EDGES * 4));
    float* h1    = (float*)(ws + alloc((size_t)N_NODES * HID_CH * 4));   // reused: h2 | agg2
    float* hbuf  = (float*)(ws + alloc((size_t)N_NODES * HID_CH * 4));   // agg1 -> h (in place)

    float* dinv = deg;
    float* agg1 = hbuf;
    float* h2   = h1;                              // first  N*32 floats
    float* agg2 = h1 + (size_t)N_NODES * OUT_CH;   // second N*32 floats

    const int B = 256;
    int gE = (N_EDGES + B - 1) / B;
    int gN = (N_NODES + B - 1) / B;
    int gRows = (N_NODES + 63) / 64;

    // ---- degree / dinv / norm ----
    hipMemsetAsync(deg, 0, (size_t)N_NODES * 4, stream);
    deg_kernel<<<gE, B, 0, stream>>>(dst, w, deg, N_EDGES);
    dinv_kernel<<<gN, B, 0, stream>>>(deg, N_NODES);
    norm_kernel<<<gE, B, 0, stream>>>(src, dst, w, dinv, norm, N_EDGES);

    // ---- layer 1 ----
    gemm_kernel<IN_CH, HID_CH><<<gRows, B, 0, stream>>>(x, W1, h1, N_NODES);
    hipMemsetAsync(agg1, 0, (size_t)N_NODES * HID_CH * 4, stream);
    {
        long long threads = (long long)N_EDGES * (HID_CH / 4);
        int blocks = (int)((threads + B - 1) / B);
        scatter_kernel<HID_CH><<<blocks, B, 0, stream>>>(src, dst, norm, h1, agg1, N_EDGES);
    }
    finalize_kernel<HID_CH, true><<<(N_NODES * (HID_CH / 4) + B - 1) / B, B, 0, stream>>>(
        agg1, h1, dinv, b1, hbuf, N_NODES);   // hbuf == agg1, in place

    // ---- layer 2 ----
    gemm_kernel<HID_CH, OUT_CH><<<gRows, B, 0, stream>>>(hbuf, W2, h2, N_NODES);
    hipMemsetAsync(agg2, 0, (size_t)N_NODES * OUT_CH * 4, stream);
    {
        long long threads = (long long)N_EDGES * (OUT_CH / 4);
        int blocks = (int)((threads + B - 1) / B);
        scatter_kernel<OUT_CH><<<blocks, B, 0, stream>>>(src, dst, norm, h2, agg2, N_EDGES);
    }
    finalize_kernel<OUT_CH, false><<<(N_NODES * (OUT_CH / 4) + B - 1) / B, B, 0, stream>>>(
        agg2, h2, dinv, b2, out, N_NODES);
}

// Round 3
// 816.796 us; speedup vs baseline: 5.3432x; 5.3432x over previous
//
#include <hip/hip_runtime.h>

#define N_NODES 100000
#define N_EDGES 3200000
#define IN_CH 128
#define HID_CH 64
#define OUT_CH 32

#define SCAN_CHUNK 512
#define NCHUNK ((N_NODES + SCAN_CHUNK - 1) / SCAN_CHUNK)   // 196

// ---------- deg[d] += w  AND  cnt[d] += 1 (int) ----------
__global__ void deg_count_kernel(const int* __restrict__ dst, const float* __restrict__ w,
                                 float* __restrict__ deg, int* __restrict__ cnt, int nE) {
    int e = blockIdx.x * blockDim.x + threadIdx.x;
    if (e >= nE) return;
    int d = dst[e];
    atomicAdd(&deg[d], w[e]);
    atomicAdd(&cnt[d], 1);
}

// ---------- dinv[i] = rsqrt(deg[i] + 1) in place ----------
__global__ void dinv_kernel(float* __restrict__ deg, int n) {
    int i = blockIdx.x * blockDim.x + threadIdx.x;
    if (i < n) deg[i] = rsqrtf(deg[i] + 1.0f);
}

// ---------- scan stage 1: per-chunk sums ----------
__global__ __launch_bounds__(256) void scan_partial_kernel(const int* __restrict__ cnt,
                                                           int* __restrict__ bsum, int n) {
    __shared__ int lds[256];
    int b = blockIdx.x, t = threadIdx.x;
    int i0 = b * SCAN_CHUNK + 2 * t;
    int s = ((i0 < n) ? cnt[i0] : 0) + ((i0 + 1 < n) ? cnt[i0 + 1] : 0);
    lds[t] = s; __syncthreads();
    for (int d = 128; d > 0; d >>= 1) { if (t < d) lds[t] += lds[t + d]; __syncthreads(); }
    if (t == 0) bsum[b] = lds[0];
}

// ---------- scan stage 2: exclusive scan of chunk sums (single wave) ----------
__global__ void scan_tops_kernel(int* __restrict__ bsum, int nchunk) {
    int lane = threadIdx.x;   // 64 lanes
    int v[4]; int base = lane * 4; int sum = 0;
#pragma unroll
    for (int k = 0; k < 4; ++k) { v[k] = (base + k < nchunk) ? bsum[base + k] : 0; sum += v[k]; }
    int incl = sum;
    for (int d = 1; d < 64; d <<= 1) { int t = __shfl_up(incl, d); if (lane >= d) incl += t; }
    int run = incl - sum;   // exclusive
#pragma unroll
    for (int k = 0; k < 4; ++k) { int old = v[k]; if (base + k < nchunk) bsum[base + k] = run; run += old; }
}

// ---------- scan stage 3: rowptr + cursor ----------
__global__ __launch_bounds__(256) void scan_write_kernel(const int* __restrict__ cnt,
                                                         const int* __restrict__ bsumx,
                                                         int* __restrict__ rowptr,
                                                         int* __restrict__ cursor, int n) {
    __shared__ int lds[256];
    int b = blockIdx.x, t = threadIdx.x;
    int i0 = b * SCAN_CHUNK + 2 * t;
    int a = (i0 < n) ? cnt[i0] : 0;
    int c = (i0 + 1 < n) ? cnt[i0 + 1] : 0;
    int pair = a + c;
    lds[t] = pair; __syncthreads();
    for (int d = 1; d < 256; d <<= 1) {
        int v = (t >= d) ? lds[t - d] : 0; __syncthreads();
        lds[t] += v; __syncthreads();
    }
    int excl = lds[t] - pair;
    int base = bsumx[b] + excl;
    if (i0 < n)     { rowptr[i0] = base;         cursor[i0] = base; }
    if (i0 + 1 < n) { rowptr[i0 + 1] = base + a; cursor[i0 + 1] = base + a; }
    if (b == 0 && t == 0) rowptr[n] = N_EDGES;
}

// ---------- CSR fill: epack[pos] = {src, norm}, norm computed inline ----------
__global__ void fill_kernel(const int* __restrict__ src, const int* __restrict__ dst,
                            const float* __restrict__ w, const float* __restrict__ dinv,
                            int* __restrict__ cursor, int2* __restrict__ epack, int nE) {
    int e = blockIdx.x * blockDim.x + threadIdx.x;
    if (e >= nE) return;
    int s = src[e], d = dst[e];
    float nr = dinv[d] * w[e] * dinv[s];
    int pos = atomicAdd(&cursor[d], 1);
    epack[pos] = make_int2(s, __float_as_int(nr));
}

// ---------- skinny GEMM: H[n x OUTC] = X[n x INC] @ W[INC x OUTC] ----------
template<int INC, int OUTC>
__global__ __launch_bounds__(256) void gemm_kernel(const float* __restrict__ X,
                                                   const float* __restrict__ Wm,
                                                   float* __restrict__ H, int n) {
    constexpr int TN = OUTC / 16;
    __shared__ float Ws[INC][OUTC];
    __shared__ float Xs[64][INC + 4];

    const int tid = threadIdx.x;
    const int row0 = blockIdx.x * 64;

    for (int i = tid; i < INC * OUTC / 4; i += 256)
        reinterpret_cast<float4*>(&Ws[0][0])[i] = reinterpret_cast<const float4*>(Wm)[i];
    for (int i = tid; i < 64 * INC / 4; i += 256) {
        int r = i / (INC / 4);
        int c = (i % (INC / 4)) * 4;
        float4 v = make_float4(0.f, 0.f, 0.f, 0.f);
        if (row0 + r < n)
            v = *reinterpret_cast<const float4*>(X + (size_t)(row0 + r) * INC + c);
        *reinterpret_cast<float4*>(&Xs[r][c]) = v;
    }
    __syncthreads();

    const int cg = tid & 15;
    const int rg = tid >> 4;

    float acc[4][TN];
#pragma unroll
    for (int i = 0; i < 4; ++i)
#pragma unroll
        for (int j = 0; j < TN; ++j) acc[i][j] = 0.f;

    for (int k = 0; k < INC; ++k) {
        float wv[TN];
#pragma unroll
        for (int j = 0; j < TN; ++j) wv[j] = Ws[k][cg * TN + j];
#pragma unroll
        for (int i = 0; i < 4; ++i) {
            float xv = Xs[rg * 4 + i][k];
#pragma unroll
            for (int j = 0; j < TN; ++j) acc[i][j] = fmaf(xv, wv[j], acc[i][j]);
        }
    }

#pragma unroll
    for (int i = 0; i < 4; ++i) {
        int row = row0 + rg * 4 + i;
        if (row < n) {
#pragma unroll
            for (int j = 0; j < TN; ++j)
                H[(size_t)row * OUTC + cg * TN + j] = acc[i][j];
        }
    }
}

// ---------- layer1 aggregate (gather) + self-loop + bias + ReLU + fused GEMM2 ----------
// one wave per node; lane = channel (HID_CH=64). Epilogue: h2 = relu_row @ W2.
__global__ __launch_bounds__(256) void aggregate1_kernel(
    const int* __restrict__ rowptr, const int2* __restrict__ epack,
    const float* __restrict__ h1, const float* __restrict__ dinv,
    const float* __restrict__ b1, const float* __restrict__ W2,
    float* __restrict__ h2, int n)
{
    __shared__ float W2s[HID_CH * OUT_CH];
    for (int i = threadIdx.x; i < HID_CH * OUT_CH / 4; i += 256)
        reinterpret_cast<float4*>(W2s)[i] = reinterpret_cast<const float4*>(W2)[i];
    __syncthreads();

    int wid = threadIdx.x >> 6;
    int lane = threadIdx.x & 63;
    int node = blockIdx.x * 4 + wid;
    if (node >= n) return;

    int beg = rowptr[node], end = rowptr[node + 1];
    float acc = 0.f;
    for (int i = beg; i < end; i += 64) {
        int nb = end - i; if (nb > 64) nb = 64;
        int2 ep = (i + lane < end) ? epack[i + lane] : make_int2(0, 0);
        int j = 0;
        for (; j + 4 <= nb; j += 4) {
            int   s0 = __shfl(ep.x, j + 0), s1 = __shfl(ep.x, j + 1);
            int   s2 = __shfl(ep.x, j + 2), s3 = __shfl(ep.x, j + 3);
            float n0 = __int_as_float(__shfl(ep.y, j + 0));
            float n1 = __int_as_float(__shfl(ep.y, j + 1));
            float n2 = __int_as_float(__shfl(ep.y, j + 2));
            float n3 = __int_as_float(__shfl(ep.y, j + 3));
            float v0 = h1[(size_t)s0 * HID_CH + lane];
            float v1 = h1[(size_t)s1 * HID_CH + lane];
            float v2 = h1[(size_t)s2 * HID_CH + lane];
            float v3 = h1[(size_t)s3 * HID_CH + lane];
            acc = fmaf(n0, v0, acc);
            acc = fmaf(n1, v1, acc);
            acc = fmaf(n2, v2, acc);
            acc = fmaf(n3, v3, acc);
        }
        for (; j < nb; ++j) {
            int s = __shfl(ep.x, j);
            float nr = __int_as_float(__shfl(ep.y, j));
            acc = fmaf(nr, h1[(size_t)s * HID_CH + lane], acc);
        }
    }
    float di = dinv[node];
    float hv = acc + di * di * h1[(size_t)node * HID_CH + lane] + b1[lane];
    hv = fmaxf(hv, 0.f);   // ReLU'd hidden value, channel = lane

    // fused GEMM2: h2[node][o] = sum_c hv(c) * W2[c][o]
    float acc2 = 0.f;
    int o = lane & 31;
#pragma unroll
    for (int c = 0; c < HID_CH; ++c) {
        float hc = __shfl(hv, c);
        acc2 = fmaf(hc, W2s[c * OUT_CH + o], acc2);
    }
    if (lane < 32) h2[(size_t)node * OUT_CH + o] = acc2;
}

// ---------- layer2 aggregate (gather) + self-loop + bias ----------
// half-wave (32 lanes) per node; lane-in-group = channel (OUT_CH=32).
__global__ __launch_bounds__(256) void aggregate2_kernel(
    const int* __restrict__ rowptr, const int2* __restrict__ epack,
    const float* __restrict__ h2, const float* __restrict__ dinv,
    const float* __restrict__ b2, float* __restrict__ out, int n)
{
    int g = threadIdx.x >> 5;        // 8 groups per block
    int lane = threadIdx.x & 31;
    int node = blockIdx.x * 8 + g;
    if (node >= n) return;

    int beg = rowptr[node], end = rowptr[node + 1];
    float acc = 0.f;
    for (int i = beg; i < end; i += 32) {
        int nb = end - i; if (nb > 32) nb = 32;
        int2 ep = (i + lane < end) ? epack[i + lane] : make_int2(0, 0);
        int j = 0;
        for (; j + 4 <= nb; j += 4) {
            int   s0 = __shfl(ep.x, j + 0, 32), s1 = __shfl(ep.x, j + 1, 32);
            int   s2 = __shfl(ep.x, j + 2, 32), s3 = __shfl(ep.x, j + 3, 32);
            float n0 = __int_as_float(__shfl(ep.y, j + 0, 32));
            float n1 = __int_as_float(__shfl(ep.y, j + 1, 32));
            float n2 = __int_as_float(__shfl(ep.y, j + 2, 32));
            float n3 = __int_as_float(__shfl(ep.y, j + 3, 32));
            float v0 = h2[(size_t)s0 * OUT_CH + lane];
            float v1 = h2[(size_t)s1 * OUT_CH + lane];
            float v2 = h2[(size_t)s2 * OUT_CH + lane];
            float v3 = h2[(size_t)s3 * OUT_CH + lane];
            acc = fmaf(n0, v0, acc);
            acc = fmaf(n1, v1, acc);
            acc = fmaf(n2, v2, acc);
            acc = fmaf(n3, v3, acc);
        }
        for (; j < nb; ++j) {
            int s = __shfl(ep.x, j, 32);
            float nr = __int_as_float(__shfl(ep.y, j, 32));
            acc = fmaf(nr, h2[(size_t)s * OUT_CH + lane], acc);
        }
    }
    float di = dinv[node];
    out[(size_t)node * OUT_CH + lane] = acc + di * di * h2[(size_t)node * OUT_CH + lane] + b2[lane];
}

extern "C" void kernel_launch(void* const* d_in, const int* in_sizes, int n_in,
                              void* d_out, int out_size, void* d_ws, size_t ws_size,
                              hipStream_t stream) {
    const float* x   = (const float*)d_in[0];
    const int*   ei  = (const int*)d_in[1];
    const float* w   = (const float*)d_in[2];
    const float* W1  = (const float*)d_in[3];
    const float* b1  = (const float*)d_in[4];
    const float* W2  = (const float*)d_in[5];
    const float* b2  = (const float*)d_in[6];
    float* out = (float*)d_out;

    const int* src = ei;
    const int* dst = ei + N_EDGES;

    // workspace layout (256B-aligned chunks); deg & cnt adjacent for one memset
    char* ws = (char*)d_ws;
    size_t off = 0;
    auto alloc = [&](size_t bytes) { size_t p = off; off += (bytes + 255) & ~(size_t)255; return p; };
    float* deg    = (float*)(ws + alloc((size_t)N_NODES * 4));          // -> dinv in place
    int*   cnt    = (int*)  (ws + alloc((size_t)N_NODES * 4));
    int*   rowptr = (int*)  (ws + alloc((size_t)(N_NODES + 1) * 4));
    int*   cursor = (int*)  (ws + alloc((size_t)N_NODES * 4));
    int*   bsum   = (int*)  (ws + alloc((size_t)NCHUNK * 4));
    int2*  epack  = (int2*) (ws + alloc((size_t)N_EDGES * 8));
    float* h1     = (float*)(ws + alloc((size_t)N_NODES * HID_CH * 4));
    float* h2     = (float*)(ws + alloc((size_t)N_NODES * OUT_CH * 4));
    float* dinv = deg;

    const int B = 256;
    int gE = (N_EDGES + B - 1) / B;
    int gN = (N_NODES + B - 1) / B;
    int gRows = (N_NODES + 63) / 64;

    // zero deg + cnt in one shot (adjacent allocations)
    size_t degPad = (((size_t)N_NODES * 4) + 255) & ~(size_t)255;
    hipMemsetAsync(deg, 0, degPad + (size_t)N_NODES * 4, stream);

    // degrees + counts, dinv
    deg_count_kernel<<<gE, B, 0, stream>>>(dst, w, deg, cnt, N_EDGES);
    dinv_kernel<<<gN, B, 0, stream>>>(deg, N_NODES);

    // CSR build: scan counts -> rowptr/cursor, then fill
    scan_partial_kernel<<<NCHUNK, B, 0, stream>>>(cnt, bsum, N_NODES);
    scan_tops_kernel<<<1, 64, 0, stream>>>(bsum, NCHUNK);
    scan_write_kernel<<<NCHUNK, B, 0, stream>>>(cnt, bsum, rowptr, cursor, N_NODES);
    fill_kernel<<<gE, B, 0, stream>>>(src, dst, w, dinv, cursor, epack, N_EDGES);

    // layer 1 GEMM: h1 = x @ W1
    gemm_kernel<IN_CH, HID_CH><<<gRows, B, 0, stream>>>(x, W1, h1, N_NODES);

    // layer 1 aggregate + ReLU + fused GEMM2 -> h2
    aggregate1_kernel<<<(N_NODES + 3) / 4, B, 0, stream>>>(rowptr, epack, h1, dinv, b1, W2, h2, N_NODES);

    // layer 2 aggregate -> out
    aggregate2_kernel<<<(N_NODES + 7) / 8, B, 0, stream>>>(rowptr, epack, h2, dinv, b2, out, N_NODES);
}

// Round 4
// 675.570 us; speedup vs baseline: 6.4601x; 1.2090x over previous
//
#include <hip/hip_runtime.h>

#define N_NODES 100000
#define N_EDGES 3200000
#define IN_CH 128
#define HID_CH 64
#define OUT_CH 32

#define SCHUNK 4096   // elements per scan block (256 threads x 16)
#define CNT_SHIFT 44
#define FRAC_MASK ((1ull << CNT_SHIFT) - 1)
#define W_SCALE 4294967296.0   // 2^32

typedef unsigned long long ull;

// ---------- packed histogram: pack[d*K + (e&K-1)] += (1<<44) | fix32(w) ----------
template<int K>
__global__ void hist_kernel(const int* __restrict__ dst, const float* __restrict__ w,
                            ull* __restrict__ pack, int nE) {
    int e = blockIdx.x * blockDim.x + threadIdx.x;
    if (e >= nE) return;
    int d = dst[e];
    ull val = ((ull)1 << CNT_SHIFT) + (ull)((double)w[e] * W_SCALE);
    atomicAdd(&pack[(size_t)d * K + (e & (K - 1))], val);
}

// ---------- dinv[i] = rsqrt(sum_k frac(pack[i*K+k]) + 1) ----------
template<int K>
__global__ void dinv_kernel(const ull* __restrict__ pack, float* __restrict__ dinv, int n) {
    int i = blockIdx.x * blockDim.x + threadIdx.x;
    if (i >= n) return;
    ull frac = 0;
#pragma unroll
    for (int k = 0; k < K; ++k) frac += (pack[(size_t)i * K + k] & FRAC_MASK);
    float deg = (float)((double)frac * (1.0 / W_SCALE));
    dinv[i] = rsqrtf(deg + 1.0f);
}

// ---------- scan stage 1: per-chunk sums of counts ----------
template<int TOTAL>
__global__ __launch_bounds__(256) void scan_partial_kernel(const ull* __restrict__ pack,
                                                           int* __restrict__ bsum) {
    __shared__ int lds[256];
    int b = blockIdx.x, t = threadIdx.x;
    int base = b * SCHUNK + t * 16;
    int s = 0;
#pragma unroll
    for (int k = 0; k < 16; ++k) {
        int i = base + k;
        if (i < TOTAL) s += (int)(pack[i] >> CNT_SHIFT);
    }
    lds[t] = s; __syncthreads();
    for (int d = 128; d > 0; d >>= 1) { if (t < d) lds[t] += lds[t + d]; __syncthreads(); }
    if (t == 0) bsum[b] = lds[0];
}

// ---------- scan stage 2: exclusive scan of chunk sums (single wave, <=256 chunks) ----------
__global__ void scan_tops_kernel(int* __restrict__ bsum, int nchunk) {
    int lane = threadIdx.x;   // 64 lanes
    int v[4]; int base = lane * 4; int sum = 0;
#pragma unroll
    for (int k = 0; k < 4; ++k) { v[k] = (base + k < nchunk) ? bsum[base + k] : 0; sum += v[k]; }
    int incl = sum;
    for (int d = 1; d < 64; d <<= 1) { int t = __shfl_up(incl, d); if (lane >= d) incl += t; }
    int run = incl - sum;   // exclusive
#pragma unroll
    for (int k = 0; k < 4; ++k) { int old = v[k]; if (base + k < nchunk) bsum[base + k] = run; run += old; }
}

// ---------- scan stage 3: write sub-segment cursors (exclusive prefix) ----------
template<int TOTAL>
__global__ __launch_bounds__(256) void scan_write_kernel(const ull* __restrict__ pack,
                                                         const int* __restrict__ bsumx,
                                                         int* __restrict__ cursor) {
    __shared__ int lds[256];
    int b = blockIdx.x, t = threadIdx.x;
    int base = b * SCHUNK + t * 16;
    int c[16]; int s = 0;
#pragma unroll
    for (int k = 0; k < 16; ++k) {
        int i = base + k;
        c[k] = (i < TOTAL) ? (int)(pack[i] >> CNT_SHIFT) : 0;
        s += c[k];
    }
    lds[t] = s; __syncthreads();
    for (int d = 1; d < 256; d <<= 1) {       // Hillis-Steele inclusive
        int v = (t >= d) ? lds[t - d] : 0; __syncthreads();
        lds[t] += v; __syncthreads();
    }
    int run = bsumx[b] + lds[t] - s;          // exclusive base for this thread
#pragma unroll
    for (int k = 0; k < 16; ++k) {
        int i = base + k;
        if (i < TOTAL) cursor[i] = run;
        run += c[k];
    }
}

// ---------- CSR fill: epack[pos] = {src, norm}; cursor advances per (d, e&K-1) ----------
template<int K>
__global__ void fill_kernel(const int* __restrict__ src, const int* __restrict__ dst,
                            const float* __restrict__ w, const float* __restrict__ dinv,
                            int* __restrict__ cursor, int2* __restrict__ epack, int nE) {
    int e = blockIdx.x * blockDim.x + threadIdx.x;
    if (e >= nE) return;
    int s = src[e], d = dst[e];
    float nr = dinv[d] * w[e] * dinv[s];
    int pos = atomicAdd(&cursor[(size_t)d * K + (e & (K - 1))], 1);
    epack[pos] = make_int2(s, __float_as_int(nr));
}

// ---------- skinny GEMM: H[n x OUTC] = X[n x INC] @ W[INC x OUTC] ----------
template<int INC, int OUTC>
__global__ __launch_bounds__(256) void gemm_kernel(const float* __restrict__ X,
                                                   const float* __restrict__ Wm,
                                                   float* __restrict__ H, int n) {
    constexpr int TN = OUTC / 16;
    __shared__ float Ws[INC][OUTC];
    __shared__ float Xs[64][INC + 4];

    const int tid = threadIdx.x;
    const int row0 = blockIdx.x * 64;

    for (int i = tid; i < INC * OUTC / 4; i += 256)
        reinterpret_cast<float4*>(&Ws[0][0])[i] = reinterpret_cast<const float4*>(Wm)[i];
    for (int i = tid; i < 64 * INC / 4; i += 256) {
        int r = i / (INC / 4);
        int c = (i % (INC / 4)) * 4;
        float4 v = make_float4(0.f, 0.f, 0.f, 0.f);
        if (row0 + r < n)
            v = *reinterpret_cast<const float4*>(X + (size_t)(row0 + r) * INC + c);
        *reinterpret_cast<float4*>(&Xs[r][c]) = v;
    }
    __syncthreads();

    const int cg = tid & 15;
    const int rg = tid >> 4;

    float acc[4][TN];
#pragma unroll
    for (int i = 0; i < 4; ++i)
#pragma unroll
        for (int j = 0; j < TN; ++j) acc[i][j] = 0.f;

    for (int k = 0; k < INC; ++k) {
        float wv[TN];
#pragma unroll
        for (int j = 0; j < TN; ++j) wv[j] = Ws[k][cg * TN + j];
#pragma unroll
        for (int i = 0; i < 4; ++i) {
            float xv = Xs[rg * 4 + i][k];
#pragma unroll
            for (int j = 0; j < TN; ++j) acc[i][j] = fmaf(xv, wv[j], acc[i][j]);
        }
    }

#pragma unroll
    for (int i = 0; i < 4; ++i) {
        int row = row0 + rg * 4 + i;
        if (row < n) {
#pragma unroll
            for (int j = 0; j < TN; ++j)
                H[(size_t)row * OUTC + cg * TN + j] = acc[i][j];
        }
    }
}

// ---------- layer1 aggregate (gather) + self-loop + bias + ReLU + fused GEMM2 ----------
template<int K>
__global__ __launch_bounds__(256) void aggregate1_kernel(
    const int* __restrict__ cursor, const int2* __restrict__ epack,
    const float* __restrict__ h1, const float* __restrict__ dinv,
    const float* __restrict__ b1, const float* __restrict__ W2,
    float* __restrict__ h2, int n)
{
    __shared__ float W2s[HID_CH * OUT_CH];
    for (int i = threadIdx.x; i < HID_CH * OUT_CH / 4; i += 256)
        reinterpret_cast<float4*>(W2s)[i] = reinterpret_cast<const float4*>(W2)[i];
    __syncthreads();

    int wid = threadIdx.x >> 6;
    int lane = threadIdx.x & 63;
    int node = blockIdx.x * 4 + wid;
    if (node >= n) return;

    // after fill, cursor[i] == start of sub-segment i+1; row = [cursor[node*K-1], cursor[node*K+K-1])
    int beg = node ? cursor[(size_t)node * K - 1] : 0;
    int end = cursor[(size_t)node * K + K - 1];

    float acc = 0.f;
    for (int i = beg; i < end; i += 64) {
        int nb = end - i; if (nb > 64) nb = 64;
        int2 ep = (i + lane < end) ? epack[i + lane] : make_int2(0, 0);
        int j = 0;
        for (; j + 4 <= nb; j += 4) {
            int   s0 = __shfl(ep.x, j + 0), s1 = __shfl(ep.x, j + 1);
            int   s2 = __shfl(ep.x, j + 2), s3 = __shfl(ep.x, j + 3);
            float n0 = __int_as_float(__shfl(ep.y, j + 0));
            float n1 = __int_as_float(__shfl(ep.y, j + 1));
            float n2 = __int_as_float(__shfl(ep.y, j + 2));
            float n3 = __int_as_float(__shfl(ep.y, j + 3));
            float v0 = h1[(size_t)s0 * HID_CH + lane];
            float v1 = h1[(size_t)s1 * HID_CH + lane];
            float v2 = h1[(size_t)s2 * HID_CH + lane];
            float v3 = h1[(size_t)s3 * HID_CH + lane];
            acc = fmaf(n0, v0, acc);
            acc = fmaf(n1, v1, acc);
            acc = fmaf(n2, v2, acc);
            acc = fmaf(n3, v3, acc);
        }
        for (; j < nb; ++j) {
            int s = __shfl(ep.x, j);
            float nr = __int_as_float(__shfl(ep.y, j));
            acc = fmaf(nr, h1[(size_t)s * HID_CH + lane], acc);
        }
    }
    float di = dinv[node];
    float hv = acc + di * di * h1[(size_t)node * HID_CH + lane] + b1[lane];
    hv = fmaxf(hv, 0.f);

    // fused GEMM2: h2[node][o] = sum_c hv(c) * W2[c][o]
    float acc2 = 0.f;
    int o = lane & 31;
#pragma unroll
    for (int c = 0; c < HID_CH; ++c) {
        float hc = __shfl(hv, c);
        acc2 = fmaf(hc, W2s[c * OUT_CH + o], acc2);
    }
    if (lane < 32) h2[(size_t)node * OUT_CH + o] = acc2;
}

// ---------- layer2 aggregate (gather) + self-loop + bias ----------
template<int K>
__global__ __launch_bounds__(256) void aggregate2_kernel(
    const int* __restrict__ cursor, const int2* __restrict__ epack,
    const float* __restrict__ h2, const float* __restrict__ dinv,
    const float* __restrict__ b2, float* __restrict__ out, int n)
{
    int g = threadIdx.x >> 5;
    int lane = threadIdx.x & 31;
    int node = blockIdx.x * 8 + g;
    if (node >= n) return;

    int beg = node ? cursor[(size_t)node * K - 1] : 0;
    int end = cursor[(size_t)node * K + K - 1];

    float acc = 0.f;
    for (int i = beg; i < end; i += 32) {
        int nb = end - i; if (nb > 32) nb = 32;
        int2 ep = (i + lane < end) ? epack[i + lane] : make_int2(0, 0);
        int j = 0;
        for (; j + 4 <= nb; j += 4) {
            int   s0 = __shfl(ep.x, j + 0, 32), s1 = __shfl(ep.x, j + 1, 32);
            int   s2 = __shfl(ep.x, j + 2, 32), s3 = __shfl(ep.x, j + 3, 32);
            float n0 = __int_as_float(__shfl(ep.y, j + 0, 32));
            float n1 = __int_as_float(__shfl(ep.y, j + 1, 32));
            float n2 = __int_as_float(__shfl(ep.y, j + 2, 32));
            float n3 = __int_as_float(__shfl(ep.y, j + 3, 32));
            float v0 = h2[(size_t)s0 * OUT_CH + lane];
            float v1 = h2[(size_t)s1 * OUT_CH + lane];
            float v2 = h2[(size_t)s2 * OUT_CH + lane];
            float v3 = h2[(size_t)s3 * OUT_CH + lane];
            acc = fmaf(n0, v0, acc);
            acc = fmaf(n1, v1, acc);
            acc = fmaf(n2, v2, acc);
            acc = fmaf(n3, v3, acc);
        }
        for (; j < nb; ++j) {
            int s = __shfl(ep.x, j, 32);
            float nr = __int_as_float(__shfl(ep.y, j, 32));
            acc = fmaf(nr, h2[(size_t)s * OUT_CH + lane], acc);
        }
    }
    float di = dinv[node];
    out[(size_t)node * OUT_CH + lane] = acc + di * di * h2[(size_t)node * OUT_CH + lane] + b2[lane];
}

// ---------- pipeline (templated on K so host can downshift if ws is tight) ----------
template<int K>
static void run_pipeline(const float* x, const int* src, const int* dst, const float* w,
                         const float* W1, const float* b1, const float* W2, const float* b2,
                         float* out, char* ws, hipStream_t stream) {
    constexpr int TOTAL = N_NODES * K;
    constexpr int NCH = (TOTAL + SCHUNK - 1) / SCHUNK;   // <= 196
    static_assert(NCH <= 256, "scan_tops capacity");

    size_t off = 0;
    auto alloc = [&](size_t b) { size_t p = off; off += (b + 255) & ~(size_t)255; return p; };
    // unionA: pack (TOTAL*8) lives hist->scan_write; h2 (N*32*4) lives agg1->agg2
    size_t unionA = alloc(((size_t)TOTAL * 8 > (size_t)N_NODES * OUT_CH * 4)
                              ? (size_t)TOTAL * 8 : (size_t)N_NODES * OUT_CH * 4);
    ull*   pack   = (ull*)(ws + unionA);
    float* h2     = (float*)(ws + unionA);
    float* dinv   = (float*)(ws + alloc((size_t)N_NODES * 4));
    int*   bsum   = (int*)  (ws + alloc((size_t)NCH * 4));
    int*   cursor = (int*)  (ws + alloc((size_t)TOTAL * 4));
    int2*  epack  = (int2*) (ws + alloc((size_t)N_EDGES * 8));
    float* h1     = (float*)(ws + alloc((size_t)N_NODES * HID_CH * 4));

    const int B = 256;
    int gE = (N_EDGES + B - 1) / B;
    int gN = (N_NODES + B - 1) / B;
    int gRows = (N_NODES + 63) / 64;

    hipMemsetAsync(pack, 0, (size_t)TOTAL * 8, stream);
    hist_kernel<K><<<gE, B, 0, stream>>>(dst, w, pack, N_EDGES);
    dinv_kernel<K><<<gN, B, 0, stream>>>(pack, dinv, N_NODES);
    scan_partial_kernel<TOTAL><<<NCH, B, 0, stream>>>(pack, bsum);
    scan_tops_kernel<<<1, 64, 0, stream>>>(bsum, NCH);
    scan_write_kernel<TOTAL><<<NCH, B, 0, stream>>>(pack, bsum, cursor);
    fill_kernel<K><<<gE, B, 0, stream>>>(src, dst, w, dinv, cursor, epack, N_EDGES);
    // pack dead from here; h2 may reuse its space
    gemm_kernel<IN_CH, HID_CH><<<gRows, B, 0, stream>>>(x, W1, h1, N_NODES);
    aggregate1_kernel<K><<<(N_NODES + 3) / 4, B, 0, stream>>>(cursor, epack, h1, dinv, b1, W2, h2, N_NODES);
    aggregate2_kernel<K><<<(N_NODES + 7) / 8, B, 0, stream>>>(cursor, epack, h2, dinv, b2, out, N_NODES);
}

template<int K>
static size_t ws_needed() {
    constexpr int TOTAL = N_NODES * K;
    auto pad = [](size_t b) { return (b + 255) & ~(size_t)255; };
    size_t unionA = ((size_t)TOTAL * 8 > (size_t)N_NODES * OUT_CH * 4)
                        ? (size_t)TOTAL * 8 : (size_t)N_NODES * OUT_CH * 4;
    return pad(unionA) + pad((size_t)N_NODES * 4) +
           pad((size_t)((TOTAL + SCHUNK - 1) / SCHUNK) * 4) + pad((size_t)TOTAL * 4) +
           pad((size_t)N_EDGES * 8) + pad((size_t)N_NODES * HID_CH * 4);
}

extern "C" void kernel_launch(void* const* d_in, const int* in_sizes, int n_in,
                              void* d_out, int out_size, void* d_ws, size_t ws_size,
                              hipStream_t stream) {
    const float* x   = (const float*)d_in[0];
    const int*   ei  = (const int*)d_in[1];
    const float* w   = (const float*)d_in[2];
    const float* W1  = (const float*)d_in[3];
    const float* b1  = (const float*)d_in[4];
    const float* W2  = (const float*)d_in[5];
    const float* b2  = (const float*)d_in[6];
    float* out = (float*)d_out;

    const int* src = ei;
    const int* dst = ei + N_EDGES;
    char* ws = (char*)d_ws;

    if (ws_size >= ws_needed<8>())
        run_pipeline<8>(x, src, dst, w, W1, b1, W2, b2, out, ws, stream);
    else
        run_pipeline<4>(x, src, dst, w, W1, b1, W2, b2, out, ws, stream);
}

// Round 7
// 656.968 us; speedup vs baseline: 6.6430x; 1.0283x over previous
//
#include <hip/hip_runtime.h>

#define N_NODES 100000
#define N_EDGES 3200000
#define IN_CH 128
#define HID_CH 64
#define OUT_CH 32

#define SCHUNK 4096   // elements per scan block (256 threads x 16)
#define CNT_SHIFT 44
#define FRAC_MASK ((1ull << CNT_SHIFT) - 1)
#define W_SCALE 4294967296.0   // 2^32

typedef unsigned long long ull;
typedef _Float16 h2v __attribute__((ext_vector_type(2)));   // half2

// ---------- packed histogram: pack[d*K + (e&K-1)] += (1<<44) | fix32(w) ----------
template<int K>
__global__ void hist_kernel(const int* __restrict__ dst, const float* __restrict__ w,
                            ull* __restrict__ pack, int nE) {
    int e = blockIdx.x * blockDim.x + threadIdx.x;
    if (e >= nE) return;
    int d = dst[e];
    ull val = ((ull)1 << CNT_SHIFT) + (ull)((double)w[e] * W_SCALE);
    atomicAdd(&pack[(size_t)d * K + (e & (K - 1))], val);
}

// ---------- dinv[i] = rsqrt(sum_k frac(pack[i*K+k]) + 1) ----------
template<int K>
__global__ void dinv_kernel(const ull* __restrict__ pack, float* __restrict__ dinv, int n) {
    int i = blockIdx.x * blockDim.x + threadIdx.x;
    if (i >= n) return;
    ull frac = 0;
#pragma unroll
    for (int k = 0; k < K; ++k) frac += (pack[(size_t)i * K + k] & FRAC_MASK);
    float deg = (float)((double)frac * (1.0 / W_SCALE));
    dinv[i] = rsqrtf(deg + 1.0f);
}

// ---------- scan stage 1: per-chunk sums of counts ----------
template<int TOTAL>
__global__ __launch_bounds__(256) void scan_partial_kernel(const ull* __restrict__ pack,
                                                           int* __restrict__ bsum) {
    __shared__ int lds[256];
    int b = blockIdx.x, t = threadIdx.x;
    int base = b * SCHUNK + t * 16;
    int s = 0;
#pragma unroll
    for (int k = 0; k < 16; ++k) {
        int i = base + k;
        if (i < TOTAL) s += (int)(pack[i] >> CNT_SHIFT);
    }
    lds[t] = s; __syncthreads();
    for (int d = 128; d > 0; d >>= 1) { if (t < d) lds[t] += lds[t + d]; __syncthreads(); }
    if (t == 0) bsum[b] = lds[0];
}

// ---------- scan stage 2: exclusive scan of chunk sums (single wave, <=256 chunks) ----------
__global__ void scan_tops_kernel(int* __restrict__ bsum, int nchunk) {
    int lane = threadIdx.x;   // 64 lanes
    int v[4]; int base = lane * 4; int sum = 0;
#pragma unroll
    for (int k = 0; k < 4; ++k) { v[k] = (base + k < nchunk) ? bsum[base + k] : 0; sum += v[k]; }
    int incl = sum;
    for (int d = 1; d < 64; d <<= 1) { int t = __shfl_up(incl, d); if (lane >= d) incl += t; }
    int run = incl - sum;   // exclusive
#pragma unroll
    for (int k = 0; k < 4; ++k) { int old = v[k]; if (base + k < nchunk) bsum[base + k] = run; run += old; }
}

// ---------- scan stage 3: write sub-segment cursors (exclusive prefix) ----------
template<int TOTAL>
__global__ __launch_bounds__(256) void scan_write_kernel(const ull* __restrict__ pack,
                                                         const int* __restrict__ bsumx,
                                                         int* __restrict__ cursor) {
    __shared__ int lds[256];
    int b = blockIdx.x, t = threadIdx.x;
    int base = b * SCHUNK + t * 16;
    int c[16]; int s = 0;
#pragma unroll
    for (int k = 0; k < 16; ++k) {
        int i = base + k;
        c[k] = (i < TOTAL) ? (int)(pack[i] >> CNT_SHIFT) : 0;
        s += c[k];
    }
    lds[t] = s; __syncthreads();
    for (int d = 1; d < 256; d <<= 1) {       // Hillis-Steele inclusive
        int v = (t >= d) ? lds[t - d] : 0; __syncthreads();
        lds[t] += v; __syncthreads();
    }
    int run = bsumx[b] + lds[t] - s;          // exclusive base for this thread
#pragma unroll
    for (int k = 0; k < 16; ++k) {
        int i = base + k;
        if (i < TOTAL) cursor[i] = run;
        run += c[k];
    }
}

// ---------- CSR fill: epack[pos] = {src, norm}; cursor advances per (d, e&K-1) ----------
template<int K>
__global__ void fill_kernel(const int* __restrict__ src, const int* __restrict__ dst,
                            const float* __restrict__ w, const float* __restrict__ dinv,
                            int* __restrict__ cursor, int2* __restrict__ epack, int nE) {
    int e = blockIdx.x * blockDim.x + threadIdx.x;
    if (e >= nE) return;
    int s = src[e], d = dst[e];
    float nr = dinv[d] * w[e] * dinv[s];
    int pos = atomicAdd(&cursor[(size_t)d * K + (e & (K - 1))], 1);
    epack[pos] = make_int2(s, __float_as_int(nr));
}

// ---------- skinny GEMM: H[n x OUTC](fp16) = X[n x INC](fp32) @ W[INC x OUTC] ----------
template<int INC, int OUTC>
__global__ __launch_bounds__(256) void gemm_kernel(const float* __restrict__ X,
                                                   const float* __restrict__ Wm,
                                                   _Float16* __restrict__ H, int n) {
    constexpr int TN = OUTC / 16;
    __shared__ float Ws[INC][OUTC];
    __shared__ float Xs[64][INC + 4];

    const int tid = threadIdx.x;
    const int row0 = blockIdx.x * 64;

    for (int i = tid; i < INC * OUTC / 4; i += 256)
        reinterpret_cast<float4*>(&Ws[0][0])[i] = reinterpret_cast<const float4*>(Wm)[i];
    for (int i = tid; i < 64 * INC / 4; i += 256) {
        int r = i / (INC / 4);
        int c = (i % (INC / 4)) * 4;
        float4 v = make_float4(0.f, 0.f, 0.f, 0.f);
        if (row0 + r < n)
            v = *reinterpret_cast<const float4*>(X + (size_t)(row0 + r) * INC + c);
        *reinterpret_cast<float4*>(&Xs[r][c]) = v;
    }
    __syncthreads();

    const int cg = tid & 15;
    const int rg = tid >> 4;

    float acc[4][TN];
#pragma unroll
    for (int i = 0; i < 4; ++i)
#pragma unroll
        for (int j = 0; j < TN; ++j) acc[i][j] = 0.f;

    for (int k = 0; k < INC; ++k) {
        float wv[TN];
#pragma unroll
        for (int j = 0; j < TN; ++j) wv[j] = Ws[k][cg * TN + j];
#pragma unroll
        for (int i = 0; i < 4; ++i) {
            float xv = Xs[rg * 4 + i][k];
#pragma unroll
            for (int j = 0; j < TN; ++j) acc[i][j] = fmaf(xv, wv[j], acc[i][j]);
        }
    }

#pragma unroll
    for (int i = 0; i < 4; ++i) {
        int row = row0 + rg * 4 + i;
        if (row < n) {
#pragma unroll
            for (int j = 0; j < TN; ++j)
                H[(size_t)row * OUTC + cg * TN + j] = (_Float16)acc[i][j];
        }
    }
}

// ---------- layer1 aggregate (fp16 gather, 2 edges in flight) + self-loop + bias
//            + ReLU + fused GEMM2 -> h2 (fp16) ----------
// one wave per node. lane = {pair p = lane&31 of 64 channels, sub = lane>>5 = edge parity}
template<int K>
__global__ __launch_bounds__(256) void aggregate1_kernel(
    const int* __restrict__ cursor, const int2* __restrict__ epack,
    const h2v* __restrict__ h1p, const float* __restrict__ dinv,
    const float* __restrict__ b1, const float* __restrict__ W2,
    _Float16* __restrict__ h2, int n)
{
    __shared__ float W2s[HID_CH * OUT_CH];
    for (int i = threadIdx.x; i < HID_CH * OUT_CH / 4; i += 256)
        reinterpret_cast<float4*>(W2s)[i] = reinterpret_cast<const float4*>(W2)[i];
    __syncthreads();

    const int wid = threadIdx.x >> 6;
    const int lane = threadIdx.x & 63;
    const int p = lane & 31;      // channel-pair index (channels 2p, 2p+1)
    const int sub = lane >> 5;    // which edge of the in-flight pair
    const int node = blockIdx.x * 4 + wid;
    if (node >= n) return;

    const int beg = node ? cursor[(size_t)node * K - 1] : 0;
    const int end = cursor[(size_t)node * K + K - 1];

    float ax = 0.f, ay = 0.f;
    for (int i = beg; i < end; i += 64) {
        int nb = end - i; if (nb > 64) nb = 64;
        int2 ep = (i + lane < end) ? epack[i + lane] : make_int2(0, 0);
        for (int j = 0; j < nb; j += 2) {
            int eidx = j + sub;                        // <= 63; OOR lanes carry (0,0)
            int s = __shfl(ep.x, eidx);
            float nr = __int_as_float(__shfl(ep.y, eidx));
            h2v hv = h1p[(size_t)s * 32 + p];
            ax = fmaf(nr, (float)hv.x, ax);
            ay = fmaf(nr, (float)hv.y, ay);
        }
    }
    // combine the two edge-parity halves: lanes l and l^32 both end with full sums
    ax += __shfl_xor(ax, 32);
    ay += __shfl_xor(ay, 32);

    const float di = dinv[node];
    const float di2 = di * di;
    h2v selfv = h1p[(size_t)node * 32 + p];
    float2 bp = reinterpret_cast<const float2*>(b1)[p];
    float hx = fmaxf(fmaf(di2, (float)selfv.x, ax) + bp.x, 0.f);
    float hy = fmaxf(fmaf(di2, (float)selfv.y, ay) + bp.y, 0.f);

    // fused GEMM2: h2[node][o] = sum_{c=0..63} hv[c] * W2[c][o]; o = lane&31,
    // sub splits the c-range (c = sub*32 .. sub*32+31), combine across sub.
    const int o = lane & 31;
    float acc2 = 0.f;
#pragma unroll
    for (int cp = 0; cp < 16; ++cp) {
        int q = sub * 16 + cp;              // source pair lane (0..31 hold all pairs)
        float hcx = __shfl(hx, q);
        float hcy = __shfl(hy, q);
        acc2 = fmaf(hcx, W2s[(2 * q + 0) * OUT_CH + o], acc2);
        acc2 = fmaf(hcy, W2s[(2 * q + 1) * OUT_CH + o], acc2);
    }
    acc2 += __shfl_xor(acc2, 32);
    if (sub == 0) h2[(size_t)node * OUT_CH + o] = (_Float16)acc2;
}

// ---------- layer2 aggregate (fp16 gather, 2 edges in flight) + self-loop + bias ----------
// 32-lane group per node. lane-in-group = {pair p = g&15 of 32 channels, sub = g>>4}
template<int K>
__global__ __launch_bounds__(256) void aggregate2_kernel(
    const int* __restrict__ cursor, const int2* __restrict__ epack,
    const h2v* __restrict__ h2p, const float* __restrict__ dinv,
    const float* __restrict__ b2, float* __restrict__ out, int n)
{
    const int grp = threadIdx.x >> 5;      // 8 groups per block
    const int g = threadIdx.x & 31;
    const int p = g & 15;
    const int sub = g >> 4;
    const int node = blockIdx.x * 8 + grp;
    if (node >= n) return;

    const int beg = node ? cursor[(size_t)node * K - 1] : 0;
    const int end = cursor[(size_t)node * K + K - 1];

    float ax = 0.f, ay = 0.f;
    for (int i = beg; i < end; i += 32) {
        int nb = end - i; if (nb > 32) nb = 32;
        int2 ep = (i + g < end) ? epack[i + g] : make_int2(0, 0);
        for (int j = 0; j < nb; j += 2) {
            int eidx = j + sub;
            int s = __shfl(ep.x, eidx, 32);
            float nr = __int_as_float(__shfl(ep.y, eidx, 32));
            h2v hv = h2p[(size_t)s * 16 + p];
            ax = fmaf(nr, (float)hv.x, ax);
            ay = fmaf(nr, (float)hv.y, ay);
        }
    }
    ax += __shfl_xor(ax, 16, 32);
    ay += __shfl_xor(ay, 16, 32);

    if (sub == 0) {
        const float di = dinv[node];
        const float di2 = di * di;
        h2v selfv = h2p[(size_t)node * 16 + p];
        float2 bp = reinterpret_cast<const float2*>(b2)[p];
        float2 r;
        r.x = fmaf(di2, (float)selfv.x, ax) + bp.x;
        r.y = fmaf(di2, (float)selfv.y, ay) + bp.y;
        reinterpret_cast<float2*>(out)[(size_t)node * 16 + p] = r;
    }
}

// ---------- pipeline (templated on K so host can downshift if ws is tight) ----------
template<int K>
static void run_pipeline(const float* x, const int* src, const int* dst, const float* w,
                         const float* W1, const float* b1, const float* W2, const float* b2,
                         float* out, char* ws, hipStream_t stream) {
    constexpr int TOTAL = N_NODES * K;
    constexpr int NCH = (TOTAL + SCHUNK - 1) / SCHUNK;
    static_assert(NCH <= 256, "scan_tops capacity");

    size_t off = 0;
    auto alloc = [&](size_t b) { size_t p = off; off += (b + 255) & ~(size_t)255; return p; };
    // unionA: pack (TOTAL*8) lives hist->scan_write; h2 (N*32*2, fp16) lives agg1->agg2
    size_t unionA = alloc(((size_t)TOTAL * 8 > (size_t)N_NODES * OUT_CH * 2)
                              ? (size_t)TOTAL * 8 : (size_t)N_NODES * OUT_CH * 2);
    ull*      pack   = (ull*)(ws + unionA);
    _Float16* h2     = (_Float16*)(ws + unionA);
    float*    dinv   = (float*)(ws + alloc((size_t)N_NODES * 4));
    int*      bsum   = (int*)  (ws + alloc((size_t)NCH * 4));
    int*      cursor = (int*)  (ws + alloc((size_t)TOTAL * 4));
    int2*     epack  = (int2*) (ws + alloc((size_t)N_EDGES * 8));
    _Float16* h1     = (_Float16*)(ws + alloc((size_t)N_NODES * HID_CH * 2));

    const int B = 256;
    int gE = (N_EDGES + B - 1) / B;
    int gN = (N_NODES + B - 1) / B;
    int gRows = (N_NODES + 63) / 64;

    hipMemsetAsync(pack, 0, (size_t)TOTAL * 8, stream);
    hist_kernel<K><<<gE, B, 0, stream>>>(dst, w, pack, N_EDGES);
    dinv_kernel<K><<<gN, B, 0, stream>>>(pack, dinv, N_NODES);
    scan_partial_kernel<TOTAL><<<NCH, B, 0, stream>>>(pack, bsum);
    scan_tops_kernel<<<1, 64, 0, stream>>>(bsum, NCH);
    scan_write_kernel<TOTAL><<<NCH, B, 0, stream>>>(pack, bsum, cursor);
    fill_kernel<K><<<gE, B, 0, stream>>>(src, dst, w, dinv, cursor, epack, N_EDGES);
    // pack dead from here; h2 reuses its space
    gemm_kernel<IN_CH, HID_CH><<<gRows, B, 0, stream>>>(x, W1, h1, N_NODES);
    aggregate1_kernel<K><<<(N_NODES + 3) / 4, B, 0, stream>>>(
        cursor, epack, (const h2v*)h1, dinv, b1, W2, h2, N_NODES);
    aggregate2_kernel<K><<<(N_NODES + 7) / 8, B, 0, stream>>>(
        cursor, epack, (const h2v*)h2, dinv, b2, out, N_NODES);
}

template<int K>
static size_t ws_needed() {
    constexpr int TOTAL = N_NODES * K;
    auto pad = [](size_t b) { return (b + 255) & ~(size_t)255; };
    size_t unionA = ((size_t)TOTAL * 8 > (size_t)N_NODES * OUT_CH * 2)
                        ? (size_t)TOTAL * 8 : (size_t)N_NODES * OUT_CH * 2;
    return pad(unionA) + pad((size_t)N_NODES * 4) +
           pad((size_t)((TOTAL + SCHUNK - 1) / SCHUNK) * 4) + pad((size_t)TOTAL * 4) +
           pad((size_t)N_EDGES * 8) + pad((size_t)N_NODES * HID_CH * 2);
}

extern "C" void kernel_launch(void* const* d_in, const int* in_sizes, int n_in,
                              void* d_out, int out_size, void* d_ws, size_t ws_size,
                              hipStream_t stream) {
    const float* x   = (const float*)d_in[0];
    const int*   ei  = (const int*)d_in[1];
    const float* w   = (const float*)d_in[2];
    const float* W1  = (const float*)d_in[3];
    const float* b1  = (const float*)d_in[4];
    const float* W2  = (const float*)d_in[5];
    const float* b2  = (const float*)d_in[6];
    float* out = (float*)d_out;

    const int* src = ei;
    const int* dst = ei + N_EDGES;
    char* ws = (char*)d_ws;

    if (ws_size >= ws_needed<8>())
        run_pipeline<8>(x, src, dst, w, W1, b1, W2, b2, out, ws, stream);
    else
        run_pipeline<4>(x, src, dst, w, W1, b1, W2, b2, out, ws, stream);
}